// Round 1
// baseline (1099.730 us; speedup 1.0000x reference)
//
#include <hip/hip_runtime.h>
#include <hip/hip_bf16.h>

typedef float fv4 __attribute__((ext_vector_type(4)));

#define HDIM 64

// ---------------------------------------------------------------------------
// pre1: u = [x|pos] @ (W1a - W1b) + b1 ; v = [x|pos] @ W1b   (D = 19)
// wave-per-node, weights held in registers (38+38 VGPRs), zero LDS.
// ---------------------------------------------------------------------------
__global__ void pre1_kernel(const float* __restrict__ x, const float* __restrict__ pos,
                            const float* __restrict__ W1, const float* __restrict__ b1,
                            float* __restrict__ U, float* __restrict__ V, int N)
{
    int lane = threadIdx.x & 63;
    int gw   = (blockIdx.x * blockDim.x + threadIdx.x) >> 6;
    int tw   = (gridDim.x * blockDim.x) >> 6;

    float wd[19], wb[19];
#pragma unroll
    for (int d = 0; d < 19; ++d) {
        float a = W1[d * HDIM + lane];
        float b = W1[(d + 19) * HDIM + lane];
        wd[d] = a - b;
        wb[d] = b;
    }
    float bb = b1[lane];

    for (int n = gw; n < N; n += tw) {
        float su = 0.f, sv = 0.f;
#pragma unroll
        for (int d4 = 0; d4 < 4; ++d4) {
            fv4 h4 = *(const fv4*)&x[(size_t)n * 16 + 4 * d4];
#pragma unroll
            for (int k = 0; k < 4; ++k) {
                su += h4[k] * wd[4 * d4 + k];
                sv += h4[k] * wb[4 * d4 + k];
            }
        }
#pragma unroll
        for (int d = 0; d < 3; ++d) {
            float h = pos[(size_t)n * 3 + d];
            su += h * wd[16 + d];
            sv += h * wb[16 + d];
        }
        U[(size_t)n * HDIM + lane] = su + bb;
        V[(size_t)n * HDIM + lane] = sv;
    }
}

// ---------------------------------------------------------------------------
// pre2: same with D = 64, h from a buffer. 128 weight VGPRs per lane.
// ---------------------------------------------------------------------------
__global__ void pre2_kernel(const float* __restrict__ h,
                            const float* __restrict__ W1, const float* __restrict__ b1,
                            float* __restrict__ U, float* __restrict__ V, int N)
{
    int lane = threadIdx.x & 63;
    int gw   = (blockIdx.x * blockDim.x + threadIdx.x) >> 6;
    int tw   = (gridDim.x * blockDim.x) >> 6;

    float wd[64], wb[64];
#pragma unroll
    for (int d = 0; d < 64; ++d) {
        float a = W1[d * HDIM + lane];
        float b = W1[(d + 64) * HDIM + lane];
        wd[d] = a - b;
        wb[d] = b;
    }
    float bb = b1[lane];

    for (int n = gw; n < N; n += tw) {
        float su = 0.f, sv = 0.f;
#pragma unroll
        for (int d4 = 0; d4 < 16; ++d4) {
            fv4 h4 = *(const fv4*)&h[(size_t)n * HDIM + 4 * d4];
#pragma unroll
            for (int k = 0; k < 4; ++k) {
                su += h4[k] * wd[4 * d4 + k];
                sv += h4[k] * wb[4 * d4 + k];
            }
        }
        U[(size_t)n * HDIM + lane] = su + bb;
        V[(size_t)n * HDIM + lane] = sv;
    }
}

// ---------------------------------------------------------------------------
// edge_conv: out[t][c] = relu( max_{k<16} ( relu(u[t]+v[src]) @ W2 )[c] + b2[c] )
// Per wave: 4 nodes = 64 edges. hrelu tile in XOR-swizzled LDS, 8x8 register
// blocking (lane (r,q): edges e = r+8i, channels c = 8q+u). LDS = 80KB exact
// -> 2 blocks/CU. out may alias U (row t only touched by owning wave).
// ---------------------------------------------------------------------------
__global__ __launch_bounds__(256, 2) void edge_conv_kernel(
    const float* __restrict__ U, const float* __restrict__ V,
    const int* __restrict__ src, const float* __restrict__ W2,
    const float* __restrict__ b2, float* __restrict__ out)
{
    __shared__ __align__(16) float W2s[64 * 64];
    __shared__ __align__(16) float At[4][64 * 64];

    int tid  = threadIdx.x;
    int wave = tid >> 6;
    int lane = tid & 63;

    // cooperative W2 load (row-major [j][c], matches m[e][j]*W2[j][c])
    for (int idx = tid * 4; idx < 4096; idx += 1024)
        *(fv4*)&W2s[idx] = *(const fv4*)&W2[idx];
    __syncthreads();

    int nodeBase = blockIdx.x * 16 + wave * 4;
    long edgeBase = (long)nodeBase * 16;
    float* at = At[wave];

    // ---- phase 1: hrelu -> swizzled LDS (lane = channel c) ----
    int c = lane;
    float uu[4];
#pragma unroll
    for (int n = 0; n < 4; ++n)
        uu[n] = U[(size_t)(nodeBase + n) * HDIM + c];

#pragma unroll
    for (int e = 0; e < 64; ++e) {
        int s = src[edgeBase + e];
        float pre = uu[e >> 4] + V[(size_t)s * HDIM + c];
        at[64 * e + (c ^ ((e & 7) << 2))] = fmaxf(pre, 0.f);
    }
    __syncthreads();

    // ---- phase 2: [64e x 64j] @ W2 with 8x8 per-lane blocking ----
    int r = lane & 7, q = lane >> 3;
    float acc[8][8];
#pragma unroll
    for (int i = 0; i < 8; ++i)
#pragma unroll
        for (int u = 0; u < 8; ++u) acc[i][u] = 0.f;

#pragma unroll
    for (int cb = 0; cb < 16; ++cb) {
        fv4 a[8];
#pragma unroll
        for (int i = 0; i < 8; ++i)
            a[i] = *(const fv4*)&at[64 * (r + 8 * i) + (((cb ^ r) << 2))];
        fv4 wlo[4], whi[4];
#pragma unroll
        for (int d2 = 0; d2 < 4; ++d2) {
            wlo[d2] = *(const fv4*)&W2s[(4 * cb + d2) * 64 + 8 * q];
            whi[d2] = *(const fv4*)&W2s[(4 * cb + d2) * 64 + 8 * q + 4];
        }
#pragma unroll
        for (int i = 0; i < 8; ++i)
#pragma unroll
            for (int d2 = 0; d2 < 4; ++d2) {
                float av = a[i][d2];
#pragma unroll
                for (int u = 0; u < 4; ++u) {
                    acc[i][u]     += av * wlo[d2][u];
                    acc[i][u + 4] += av * whi[d2][u];
                }
            }
    }

    // ---- per-lane pair max (edges r+8*(2n), r+8*(2n+1) are both in node n) ----
    float mx[4][8];
#pragma unroll
    for (int n = 0; n < 4; ++n)
#pragma unroll
        for (int u = 0; u < 8; ++u)
            mx[n][u] = fmaxf(acc[2 * n][u], acc[2 * n + 1][u]);

    // ---- butterfly max across the 8 r-lanes (lane bits 0..2) ----
#pragma unroll
    for (int d = 1; d <= 4; d <<= 1)
#pragma unroll
        for (int n = 0; n < 4; ++n)
#pragma unroll
            for (int u = 0; u < 8; ++u)
                mx[n][u] = fmaxf(mx[n][u], __shfl_xor(mx[n][u], d));

    // ---- store: lane r<4 writes node nodeBase+r, channels 8q..8q+7 ----
    if (r < 4) {
        fv4 blo = *(const fv4*)&b2[8 * q];
        fv4 bhi = *(const fv4*)&b2[8 * q + 4];
        fv4 o0, o1;
#pragma unroll
        for (int u = 0; u < 4; ++u) {
            o0[u] = fmaxf(mx[r][u] + blo[u], 0.f);
            o1[u] = fmaxf(mx[r][u + 4] + bhi[u], 0.f);
        }
        float* op = &out[(size_t)(nodeBase + r) * HDIM + 8 * q];
        *(fv4*)op       = o0;
        *(fv4*)(op + 4) = o1;
    }
}

// ---------------------------------------------------------------------------
// region mean accumulation: qsums[r][c] += h[n][c], qcnt[r] += 1
// ---------------------------------------------------------------------------
__global__ void region_mean_kernel(const float* __restrict__ h, const int* __restrict__ labels,
                                   float* __restrict__ qsums, int* __restrict__ qcnt, int N)
{
    __shared__ float ls[8 * 64];
    __shared__ int   lc[8];
    int tid  = threadIdx.x;
    int lane = tid & 63;
    int gw   = (blockIdx.x * blockDim.x + tid) >> 6;
    int tw   = (gridDim.x * blockDim.x) >> 6;

    float acc[8] = {0, 0, 0, 0, 0, 0, 0, 0};
    int   cnt[8] = {0, 0, 0, 0, 0, 0, 0, 0};

    for (int n = gw; n < N; n += tw) {
        int lbl = labels[n];
        float val = h[(size_t)n * HDIM + lane];
#pragma unroll
        for (int r = 0; r < 8; ++r) {
            acc[r] += (lbl == r) ? val : 0.f;
            cnt[r] += (lbl == r) ? 1 : 0;
        }
    }

    if (tid < 8) lc[tid] = 0;
    for (int idx = tid; idx < 512; idx += 256) ls[idx] = 0.f;
    __syncthreads();
#pragma unroll
    for (int r = 0; r < 8; ++r) atomicAdd(&ls[r * 64 + lane], acc[r]);
    if (lane == 0)
#pragma unroll
        for (int r = 0; r < 8; ++r) atomicAdd(&lc[r], cnt[r]);
    __syncthreads();
    for (int idx = tid; idx < 512; idx += 256) atomicAdd(&qsums[idx], ls[idx]);
    if (tid < 8) atomicAdd(&qcnt[tid], lc[tid]);
}

// ---------------------------------------------------------------------------
// tail: qx = mean; conv3, conv4 on quotient graph (8 nodes, ~32 edges);
// global add pool; final linear. Single block.
// ---------------------------------------------------------------------------
__global__ void tail_kernel(const float* __restrict__ qsums, const int* __restrict__ qcnt,
                            const int* __restrict__ qei, int Eq,
                            const float* __restrict__ W31, const float* __restrict__ b31,
                            const float* __restrict__ W32, const float* __restrict__ b32,
                            const float* __restrict__ W41, const float* __restrict__ b41,
                            const float* __restrict__ W42, const float* __restrict__ b42,
                            const float* __restrict__ linW, const float* __restrict__ linb,
                            float* __restrict__ out)
{
    __shared__ float qx[8 * 64], uu[8 * 64], vv[8 * 64], agg[8 * 64], hr[64], emb[64];
    int tid = threadIdx.x;

    for (int idx = tid; idx < 512; idx += 256) {
        int r = idx >> 6;
        int cc = qcnt[r];
        qx[idx] = (cc > 0) ? qsums[idx] / (float)cc : 0.f;
    }
    __syncthreads();

    for (int layer = 0; layer < 2; ++layer) {
        const float* W1p = layer ? W41 : W31;
        const float* b1p = layer ? b41 : b31;
        const float* W2p = layer ? W42 : W32;
        const float* b2p = layer ? b42 : b32;

        for (int idx = tid; idx < 512; idx += 256) {
            int t = idx >> 6, c = idx & 63;
            float su = 0.f, sv = 0.f;
            for (int d = 0; d < 64; ++d) {
                float hv = qx[t * 64 + d];
                float a = W1p[d * 64 + c];
                float b = W1p[(d + 64) * 64 + c];
                su += hv * (a - b);
                sv += hv * b;
            }
            uu[idx] = su + b1p[c];
            vv[idx] = sv;
        }
        for (int idx = tid; idx < 512; idx += 256) agg[idx] = -INFINITY;
        __syncthreads();

        for (int e = 0; e < Eq; ++e) {
            int s = qei[e];
            int t = qei[Eq + e];
            if (tid < 64) hr[tid] = fmaxf(uu[t * 64 + tid] + vv[s * 64 + tid], 0.f);
            __syncthreads();
            if (tid < 64) {
                float m = 0.f;
                for (int j = 0; j < 64; ++j) m += hr[j] * W2p[j * 64 + tid];
                agg[t * 64 + tid] = fmaxf(agg[t * 64 + tid], m);
            }
            __syncthreads();
        }

        for (int idx = tid; idx < 512; idx += 256) {
            int c = idx & 63;
            float a = agg[idx];
            float vout = (a == -INFINITY) ? 0.f : (a + b2p[c]);
            qx[idx] = fmaxf(vout, 0.f);
        }
        __syncthreads();
    }

    if (tid < 64) {
        float s = 0.f;
        for (int r = 0; r < 8; ++r) s += qx[r * 64 + tid];
        emb[tid] = s;
    }
    __syncthreads();
    if (tid < 8) {
        float o = linb[tid];
        for (int c = 0; c < 64; ++c) o += emb[c] * linW[c * 8 + tid];
        out[tid] = o;
    }
}

// ---------------------------------------------------------------------------
extern "C" void kernel_launch(void* const* d_in, const int* in_sizes, int n_in,
                              void* d_out, int out_size, void* d_ws, size_t ws_size,
                              hipStream_t stream)
{
    const float* x    = (const float*)d_in[0];
    const float* pos  = (const float*)d_in[1];
    const int*   ei   = (const int*)d_in[2];
    const int*   lbl  = (const int*)d_in[3];
    const int*   qei  = (const int*)d_in[4];
    const float* W11 = (const float*)d_in[5];
    const float* b11 = (const float*)d_in[6];
    const float* W12 = (const float*)d_in[7];
    const float* b12 = (const float*)d_in[8];
    const float* W21 = (const float*)d_in[9];
    const float* b21 = (const float*)d_in[10];
    const float* W22 = (const float*)d_in[11];
    const float* b22 = (const float*)d_in[12];
    const float* W31 = (const float*)d_in[13];
    const float* b31 = (const float*)d_in[14];
    const float* W32 = (const float*)d_in[15];
    const float* b32 = (const float*)d_in[16];
    const float* W41 = (const float*)d_in[17];
    const float* b41 = (const float*)d_in[18];
    const float* W42 = (const float*)d_in[19];
    const float* b42 = (const float*)d_in[20];
    const float* linW = (const float*)d_in[21];
    const float* linb = (const float*)d_in[22];

    int N  = in_sizes[0] / 16;          // 100000
    int Eq = in_sizes[4] / 2;           // ~32
    const int* src = ei;                // row 0 = src; tgt is repeat(arange(N),16)

    size_t NH = (size_t)N * HDIM;
    float* bufA  = (float*)d_ws;        // U1 / h1 / (aliased out of edge1)
    float* bufB  = bufA + NH;           // V1 / U2 / h2
    float* bufC  = bufB + NH;           // V2
    float* qsums = bufC + NH;           // 512 floats
    int*   qcnt  = (int*)(qsums + 512); // 8 ints

    hipMemsetAsync(qsums, 0, 512 * sizeof(float) + 8 * sizeof(int), stream);

    int edgeBlocks = N / 16;            // 6250

    // conv1
    pre1_kernel<<<512, 256, 0, stream>>>(x, pos, W11, b11, bufA, bufB, N);
    edge_conv_kernel<<<edgeBlocks, 256, 0, stream>>>(bufA, bufB, src, W12, b12, bufA);
    // conv2
    pre2_kernel<<<512, 256, 0, stream>>>(bufA, W21, b21, bufB, bufC, N);
    edge_conv_kernel<<<edgeBlocks, 256, 0, stream>>>(bufB, bufC, src, W22, b22, bufB);
    // quotient pooling + tail
    region_mean_kernel<<<128, 256, 0, stream>>>(bufB, lbl, qsums, qcnt, N);
    tail_kernel<<<1, 256, 0, stream>>>(qsums, qcnt, qei, Eq,
                                       W31, b31, W32, b32,
                                       W41, b41, W42, b42,
                                       linW, linb, (float*)d_out);
}

// Round 2
// 768.232 us; speedup vs baseline: 1.4315x; 1.4315x over previous
//
#include <hip/hip_runtime.h>
#include <hip/hip_bf16.h>

typedef float fv4 __attribute__((ext_vector_type(4)));

#define HDIM 64

// ---------------------------------------------------------------------------
// pre1: u = [x|pos] @ (W1a - W1b) + b1 ; v = [x|pos] @ W1b   (D = 19)
// wave-per-node-stride, weights in registers (38+38), launch_bounds to
// guarantee no scratch spill.
// ---------------------------------------------------------------------------
__global__ __launch_bounds__(256, 2) void pre1_kernel(
    const float* __restrict__ x, const float* __restrict__ pos,
    const float* __restrict__ W1, const float* __restrict__ b1,
    float* __restrict__ U, float* __restrict__ V, int N)
{
    int lane = threadIdx.x & 63;
    int gw   = (blockIdx.x * blockDim.x + threadIdx.x) >> 6;
    int tw   = (gridDim.x * blockDim.x) >> 6;

    float wd[19], wb[19];
#pragma unroll
    for (int d = 0; d < 19; ++d) {
        float a = W1[d * HDIM + lane];
        float b = W1[(d + 19) * HDIM + lane];
        wd[d] = a - b;
        wb[d] = b;
    }
    float bb = b1[lane];

    for (int n = gw; n < N; n += tw) {
        float su = 0.f, sv = 0.f;
#pragma unroll
        for (int d4 = 0; d4 < 4; ++d4) {
            fv4 h4 = *(const fv4*)&x[(size_t)n * 16 + 4 * d4];
#pragma unroll
            for (int k = 0; k < 4; ++k) {
                su += h4[k] * wd[4 * d4 + k];
                sv += h4[k] * wb[4 * d4 + k];
            }
        }
#pragma unroll
        for (int d = 0; d < 3; ++d) {
            float h = pos[(size_t)n * 3 + d];
            su += h * wd[16 + d];
            sv += h * wb[16 + d];
        }
        U[(size_t)n * HDIM + lane] = su + bb;
        V[(size_t)n * HDIM + lane] = sv;
    }
}

// ---------------------------------------------------------------------------
// pre_wide (D=64): job-split across waves. Even waves compute U = h@(W1a-W1b)+b1,
// odd waves compute V = h@W1b. Only 64 weight VGPRs per lane -> no spill
// (R1 post-mortem: 128-reg version spilled to scratch, VGPR_Count=64,
//  VALUBusy 1.1%, 300us). 4 partial sums break the FMA dependence chain.
// ---------------------------------------------------------------------------
__global__ __launch_bounds__(256, 2) void pre_wide_kernel(
    const float* __restrict__ h,
    const float* __restrict__ W1, const float* __restrict__ b1,
    float* __restrict__ U, float* __restrict__ V, int N)
{
    int lane = threadIdx.x & 63;
    int gw   = (blockIdx.x * blockDim.x + threadIdx.x) >> 6;
    int tw   = (gridDim.x * blockDim.x) >> 6;
    int job  = gw & 1;     // wave-uniform
    int w    = gw >> 1;
    int nw   = tw >> 1;

    float wt[64];
    if (job == 0) {
#pragma unroll
        for (int d = 0; d < 64; ++d)
            wt[d] = W1[d * HDIM + lane] - W1[(d + 64) * HDIM + lane];
    } else {
#pragma unroll
        for (int d = 0; d < 64; ++d)
            wt[d] = W1[(d + 64) * HDIM + lane];
    }
    float bb = (job == 0) ? b1[lane] : 0.f;
    float* __restrict__ out = (job == 0) ? U : V;

    for (int n = w; n < N; n += nw) {
        float s0 = 0.f, s1 = 0.f, s2 = 0.f, s3 = 0.f;
#pragma unroll
        for (int d4 = 0; d4 < 16; ++d4) {
            fv4 h4 = *(const fv4*)&h[(size_t)n * HDIM + 4 * d4];
            s0 += h4[0] * wt[4 * d4 + 0];
            s1 += h4[1] * wt[4 * d4 + 1];
            s2 += h4[2] * wt[4 * d4 + 2];
            s3 += h4[3] * wt[4 * d4 + 3];
        }
        out[(size_t)n * HDIM + lane] = (s0 + s1) + (s2 + s3) + bb;
    }
}

// ---------------------------------------------------------------------------
// edge_conv: out[t][c] = relu( max_{k<16} ( relu(u[t]+v[src]) @ W2 )[c] + b2[c] )
// Per wave: 4 nodes = 64 edges. hrelu tile in XOR-swizzled LDS, 8x8 register
// blocking. LDS = 80KB exact -> 2 blocks/CU. out may alias U.
// ---------------------------------------------------------------------------
__global__ __launch_bounds__(256, 2) void edge_conv_kernel(
    const float* __restrict__ U, const float* __restrict__ V,
    const int* __restrict__ src, const float* __restrict__ W2,
    const float* __restrict__ b2, float* __restrict__ out)
{
    __shared__ __align__(16) float W2s[64 * 64];
    __shared__ __align__(16) float At[4][64 * 64];

    int tid  = threadIdx.x;
    int wave = tid >> 6;
    int lane = tid & 63;

    for (int idx = tid * 4; idx < 4096; idx += 1024)
        *(fv4*)&W2s[idx] = *(const fv4*)&W2[idx];
    __syncthreads();

    int nodeBase = blockIdx.x * 16 + wave * 4;
    long edgeBase = (long)nodeBase * 16;
    float* at = At[wave];

    // ---- phase 1: hrelu -> swizzled LDS (lane = channel c) ----
    int c = lane;
    float uu[4];
#pragma unroll
    for (int n = 0; n < 4; ++n)
        uu[n] = U[(size_t)(nodeBase + n) * HDIM + c];

#pragma unroll
    for (int e = 0; e < 64; ++e) {
        int s = src[edgeBase + e];
        float pre = uu[e >> 4] + V[(size_t)s * HDIM + c];
        at[64 * e + (c ^ ((e & 7) << 2))] = fmaxf(pre, 0.f);
    }
    __syncthreads();

    // ---- phase 2: [64e x 64j] @ W2 with 8x8 per-lane blocking ----
    int r = lane & 7, q = lane >> 3;
    float acc[8][8];
#pragma unroll
    for (int i = 0; i < 8; ++i)
#pragma unroll
        for (int u = 0; u < 8; ++u) acc[i][u] = 0.f;

#pragma unroll
    for (int cb = 0; cb < 16; ++cb) {
        fv4 a[8];
#pragma unroll
        for (int i = 0; i < 8; ++i)
            a[i] = *(const fv4*)&at[64 * (r + 8 * i) + (((cb ^ r) << 2))];
        fv4 wlo[4], whi[4];
#pragma unroll
        for (int d2 = 0; d2 < 4; ++d2) {
            wlo[d2] = *(const fv4*)&W2s[(4 * cb + d2) * 64 + 8 * q];
            whi[d2] = *(const fv4*)&W2s[(4 * cb + d2) * 64 + 8 * q + 4];
        }
#pragma unroll
        for (int i = 0; i < 8; ++i)
#pragma unroll
            for (int d2 = 0; d2 < 4; ++d2) {
                float av = a[i][d2];
#pragma unroll
                for (int u = 0; u < 4; ++u) {
                    acc[i][u]     += av * wlo[d2][u];
                    acc[i][u + 4] += av * whi[d2][u];
                }
            }
    }

    float mx[4][8];
#pragma unroll
    for (int n = 0; n < 4; ++n)
#pragma unroll
        for (int u = 0; u < 8; ++u)
            mx[n][u] = fmaxf(acc[2 * n][u], acc[2 * n + 1][u]);

#pragma unroll
    for (int d = 1; d <= 4; d <<= 1)
#pragma unroll
        for (int n = 0; n < 4; ++n)
#pragma unroll
            for (int u = 0; u < 8; ++u)
                mx[n][u] = fmaxf(mx[n][u], __shfl_xor(mx[n][u], d));

    if (r < 4) {
        fv4 blo = *(const fv4*)&b2[8 * q];
        fv4 bhi = *(const fv4*)&b2[8 * q + 4];
        fv4 o0, o1;
#pragma unroll
        for (int u = 0; u < 4; ++u) {
            o0[u] = fmaxf(mx[r][u] + blo[u], 0.f);
            o1[u] = fmaxf(mx[r][u + 4] + bhi[u], 0.f);
        }
        float* op = &out[(size_t)(nodeBase + r) * HDIM + 8 * q];
        *(fv4*)op       = o0;
        *(fv4*)(op + 4) = o1;
    }
}

// ---------------------------------------------------------------------------
// region mean accumulation
// ---------------------------------------------------------------------------
__global__ void region_mean_kernel(const float* __restrict__ h, const int* __restrict__ labels,
                                   float* __restrict__ qsums, int* __restrict__ qcnt, int N)
{
    __shared__ float ls[8 * 64];
    __shared__ int   lc[8];
    int tid  = threadIdx.x;
    int lane = tid & 63;
    int gw   = (blockIdx.x * blockDim.x + tid) >> 6;
    int tw   = (gridDim.x * blockDim.x) >> 6;

    float acc[8] = {0, 0, 0, 0, 0, 0, 0, 0};
    int   cnt[8] = {0, 0, 0, 0, 0, 0, 0, 0};

    for (int n = gw; n < N; n += tw) {
        int lbl = labels[n];
        float val = h[(size_t)n * HDIM + lane];
#pragma unroll
        for (int r = 0; r < 8; ++r) {
            acc[r] += (lbl == r) ? val : 0.f;
            cnt[r] += (lbl == r) ? 1 : 0;
        }
    }

    if (tid < 8) lc[tid] = 0;
    for (int idx = tid; idx < 512; idx += 256) ls[idx] = 0.f;
    __syncthreads();
#pragma unroll
    for (int r = 0; r < 8; ++r) atomicAdd(&ls[r * 64 + lane], acc[r]);
    if (lane == 0)
#pragma unroll
        for (int r = 0; r < 8; ++r) atomicAdd(&lc[r], cnt[r]);
    __syncthreads();
    for (int idx = tid; idx < 512; idx += 256) atomicAdd(&qsums[idx], ls[idx]);
    if (tid < 8) atomicAdd(&qcnt[tid], lc[tid]);
}

// ---------------------------------------------------------------------------
// tail (rewritten R2): fully parallel. No serial edge loop, W2 + edge lists
// staged in LDS, coalesced global weight reads for u/v. (R1: 265us of pure
// single-CU global-latency serialization -> predict ~10us.)
// ---------------------------------------------------------------------------
#define EQ_MAX 64
__global__ void tail_kernel(const float* __restrict__ qsums, const int* __restrict__ qcnt,
                            const int* __restrict__ qei, int Eq,
                            const float* __restrict__ W31, const float* __restrict__ b31,
                            const float* __restrict__ W32, const float* __restrict__ b32,
                            const float* __restrict__ W41, const float* __restrict__ b41,
                            const float* __restrict__ W42, const float* __restrict__ b42,
                            const float* __restrict__ linW, const float* __restrict__ linb,
                            float* __restrict__ out)
{
    __shared__ float qx[512], uu[512], vv[512];
    __shared__ float hr[EQ_MAX * 64], me[EQ_MAX * 64];
    __shared__ __align__(16) float W2s[64 * 64];
    __shared__ int   qes[EQ_MAX], qet[EQ_MAX];
    __shared__ float emb[64];

    int tid = threadIdx.x;
    if (Eq > EQ_MAX) Eq = EQ_MAX;

    if (tid < Eq) { qes[tid] = qei[tid]; qet[tid] = qei[Eq + tid]; }
    for (int idx = tid; idx < 512; idx += 256) {
        int r = idx >> 6;
        int cc = qcnt[r];
        qx[idx] = (cc > 0) ? qsums[idx] / (float)cc : 0.f;
    }
    __syncthreads();

    for (int layer = 0; layer < 2; ++layer) {
        const float* W1p = layer ? W41 : W31;
        const float* b1p = layer ? b41 : b31;
        const float* W2p = layer ? W42 : W32;
        const float* b2p = layer ? b42 : b32;

        // stage W2 (coalesced, 16KB)
        for (int idx = tid * 4; idx < 4096; idx += 1024)
            *(fv4*)&W2s[idx] = *(const fv4*)&W2p[idx];

        // u/v for all 8 quotient nodes; thread (t = idx>>6, c = idx&63)
        for (int idx = tid; idx < 512; idx += 256) {
            int t = idx >> 6, c = idx & 63;
            float su = 0.f, sv = 0.f;
#pragma unroll 8
            for (int d = 0; d < 64; ++d) {
                float hv = qx[t * 64 + d];
                float a = W1p[d * 64 + c];
                float b = W1p[(d + 64) * 64 + c];
                su += hv * (a - b);
                sv += hv * b;
            }
            uu[idx] = su + b1p[c];
            vv[idx] = sv;
        }
        __syncthreads();

        // hr[e][c] = relu(u[tgt] + v[src]) for all edges in parallel
        for (int idx = tid; idx < Eq * 64; idx += 256) {
            int e = idx >> 6, c = idx & 63;
            hr[idx] = fmaxf(uu[qet[e] * 64 + c] + vv[qes[e] * 64 + c], 0.f);
        }
        __syncthreads();

        // me[e][c] = hr[e] @ W2
        {
            int c = tid & 63, e0 = tid >> 6;
            for (int e = e0; e < Eq; e += 4) {
                float acc = 0.f;
#pragma unroll 8
                for (int j = 0; j < 64; ++j)
                    acc += hr[e * 64 + j] * W2s[j * 64 + c];
                me[e * 64 + c] = acc;
            }
        }
        __syncthreads();

        // segment max over edges per target, +b2, relu, write back to qx
        for (int idx = tid; idx < 512; idx += 256) {
            int t = idx >> 6, c = idx & 63;
            float a = -INFINITY;
            for (int e = 0; e < Eq; ++e)
                if (qet[e] == t) a = fmaxf(a, me[e * 64 + c]);
            float vout = (a == -INFINITY) ? 0.f : (a + b2p[c]);
            qx[idx] = fmaxf(vout, 0.f);
        }
        __syncthreads();
    }

    if (tid < 64) {
        float s = 0.f;
        for (int r = 0; r < 8; ++r) s += qx[r * 64 + tid];
        emb[tid] = s;
    }
    __syncthreads();
    if (tid < 8) {
        float o = linb[tid];
        for (int c = 0; c < 64; ++c) o += emb[c] * linW[c * 8 + tid];
        out[tid] = o;
    }
}

// ---------------------------------------------------------------------------
extern "C" void kernel_launch(void* const* d_in, const int* in_sizes, int n_in,
                              void* d_out, int out_size, void* d_ws, size_t ws_size,
                              hipStream_t stream)
{
    const float* x    = (const float*)d_in[0];
    const float* pos  = (const float*)d_in[1];
    const int*   ei   = (const int*)d_in[2];
    const int*   lbl  = (const int*)d_in[3];
    const int*   qei  = (const int*)d_in[4];
    const float* W11 = (const float*)d_in[5];
    const float* b11 = (const float*)d_in[6];
    const float* W12 = (const float*)d_in[7];
    const float* b12 = (const float*)d_in[8];
    const float* W21 = (const float*)d_in[9];
    const float* b21 = (const float*)d_in[10];
    const float* W22 = (const float*)d_in[11];
    const float* b22 = (const float*)d_in[12];
    const float* W31 = (const float*)d_in[13];
    const float* b31 = (const float*)d_in[14];
    const float* W32 = (const float*)d_in[15];
    const float* b32 = (const float*)d_in[16];
    const float* W41 = (const float*)d_in[17];
    const float* b41 = (const float*)d_in[18];
    const float* W42 = (const float*)d_in[19];
    const float* b42 = (const float*)d_in[20];
    const float* linW = (const float*)d_in[21];
    const float* linb = (const float*)d_in[22];

    int N  = in_sizes[0] / 16;          // 100000
    int Eq = in_sizes[4] / 2;           // 32
    const int* src = ei;                // row 0 = src; tgt = repeat(arange(N),16)

    size_t NH = (size_t)N * HDIM;
    float* bufA  = (float*)d_ws;        // U1 / h1
    float* bufB  = bufA + NH;           // V1 / U2 / h2
    float* bufC  = bufB + NH;           // V2
    float* qsums = bufC + NH;           // 512 floats
    int*   qcnt  = (int*)(qsums + 512); // 8 ints

    hipMemsetAsync(qsums, 0, 512 * sizeof(float) + 8 * sizeof(int), stream);

    int edgeBlocks = N / 16;            // 6250

    // conv1
    pre1_kernel<<<512, 256, 0, stream>>>(x, pos, W11, b11, bufA, bufB, N);
    edge_conv_kernel<<<edgeBlocks, 256, 0, stream>>>(bufA, bufB, src, W12, b12, bufA);
    // conv2
    pre_wide_kernel<<<512, 256, 0, stream>>>(bufA, W21, b21, bufB, bufC, N);
    edge_conv_kernel<<<edgeBlocks, 256, 0, stream>>>(bufB, bufC, src, W22, b22, bufB);
    // quotient pooling + tail
    region_mean_kernel<<<128, 256, 0, stream>>>(bufB, lbl, qsums, qcnt, N);
    tail_kernel<<<1, 256, 0, stream>>>(qsums, qcnt, qei, Eq,
                                       W31, b31, W32, b32,
                                       W41, b41, W42, b42,
                                       linW, linb, (float*)d_out);
}

// Round 3
// 511.707 us; speedup vs baseline: 2.1491x; 1.5013x over previous
//
#include <hip/hip_runtime.h>
#include <hip/hip_bf16.h>

typedef float fv4 __attribute__((ext_vector_type(4)));
using bf8  = __attribute__((ext_vector_type(8))) short;  // 8 bf16 = 4 VGPRs (MFMA A/B frag)
using f32x4 = __attribute__((ext_vector_type(4))) float; // MFMA C/D frag

#define HDIM 64

// round-to-nearest-even fp32 -> bf16 bits
__device__ __forceinline__ unsigned bf16r(float f) {
    unsigned u = __float_as_uint(f);
    return (u + 0x7fffu + ((u >> 16) & 1u)) >> 16;
}
__device__ __forceinline__ float bf16lo2f(unsigned p) { return __uint_as_float(p << 16); }
__device__ __forceinline__ float bf16hi2f(unsigned p) { return __uint_as_float(p & 0xffff0000u); }

// ---------------------------------------------------------------------------
// w2prep: split W2 (fp32 [j][c]) into transposed bf16 hi/lo pair Wt[c][j].
// hi+lo recovers ~16 mantissa bits -> removes the systematic (mean-surviving)
// weight-quantization error from the MFMA path. Both convs in one launch.
// ---------------------------------------------------------------------------
__global__ void w2prep_kernel(const float* __restrict__ W2a, const float* __restrict__ W2b,
                              unsigned short* __restrict__ hiA, unsigned short* __restrict__ loA,
                              unsigned short* __restrict__ hiB, unsigned short* __restrict__ loB)
{
    int idx = blockIdx.x * 256 + threadIdx.x;
    if (idx < 4096) {
        int j = idx >> 6, c = idx & 63;
        float w = W2a[idx];
        unsigned h = bf16r(w);
        unsigned l = bf16r(w - __uint_as_float(h << 16));
        hiA[c * 64 + j] = (unsigned short)h; loA[c * 64 + j] = (unsigned short)l;
        w = W2b[idx];
        h = bf16r(w);
        l = bf16r(w - __uint_as_float(h << 16));
        hiB[c * 64 + j] = (unsigned short)h; loB[c * 64 + j] = (unsigned short)l;
    }
}

// ---------------------------------------------------------------------------
// pre1: u = [x|pos] @ (W1a - W1b) + b1 ; v = [x|pos] @ W1b   (D = 19)
// fp32 math, bf16 outputs (halves edge-kernel gather bytes).
// ---------------------------------------------------------------------------
__global__ __launch_bounds__(256, 2) void pre1_kernel(
    const float* __restrict__ x, const float* __restrict__ pos,
    const float* __restrict__ W1, const float* __restrict__ b1,
    unsigned short* __restrict__ U, unsigned short* __restrict__ V, int N)
{
    int lane = threadIdx.x & 63;
    int gw   = (blockIdx.x * blockDim.x + threadIdx.x) >> 6;
    int tw   = (gridDim.x * blockDim.x) >> 6;

    float wd[19], wb[19];
#pragma unroll
    for (int d = 0; d < 19; ++d) {
        float a = W1[d * HDIM + lane];
        float b = W1[(d + 19) * HDIM + lane];
        wd[d] = a - b;
        wb[d] = b;
    }
    float bb = b1[lane];

    for (int n = gw; n < N; n += tw) {
        float su = 0.f, sv = 0.f;
#pragma unroll
        for (int d4 = 0; d4 < 4; ++d4) {
            fv4 h4 = *(const fv4*)&x[(size_t)n * 16 + 4 * d4];
#pragma unroll
            for (int k = 0; k < 4; ++k) {
                su += h4[k] * wd[4 * d4 + k];
                sv += h4[k] * wb[4 * d4 + k];
            }
        }
#pragma unroll
        for (int d = 0; d < 3; ++d) {
            float h = pos[(size_t)n * 3 + d];
            su += h * wd[16 + d];
            sv += h * wb[16 + d];
        }
        U[(size_t)n * HDIM + lane] = (unsigned short)bf16r(su + bb);
        V[(size_t)n * HDIM + lane] = (unsigned short)bf16r(sv);
    }
}

// ---------------------------------------------------------------------------
// pre_wide (D=64): job-split across waves (64 weight VGPRs -> no spill).
// bf16 outputs.
// ---------------------------------------------------------------------------
__global__ __launch_bounds__(256, 2) void pre_wide_kernel(
    const float* __restrict__ h,
    const float* __restrict__ W1, const float* __restrict__ b1,
    unsigned short* __restrict__ U, unsigned short* __restrict__ V, int N)
{
    int lane = threadIdx.x & 63;
    int gw   = (blockIdx.x * blockDim.x + threadIdx.x) >> 6;
    int tw   = (gridDim.x * blockDim.x) >> 6;
    int job  = gw & 1;
    int w    = gw >> 1;
    int nw   = tw >> 1;

    float wt[64];
    if (job == 0) {
#pragma unroll
        for (int d = 0; d < 64; ++d)
            wt[d] = W1[d * HDIM + lane] - W1[(d + 64) * HDIM + lane];
    } else {
#pragma unroll
        for (int d = 0; d < 64; ++d)
            wt[d] = W1[(d + 64) * HDIM + lane];
    }
    float bb = (job == 0) ? b1[lane] : 0.f;
    unsigned short* __restrict__ out = (job == 0) ? U : V;

    for (int n = w; n < N; n += nw) {
        float s0 = 0.f, s1 = 0.f, s2 = 0.f, s3 = 0.f;
#pragma unroll
        for (int d4 = 0; d4 < 16; ++d4) {
            fv4 h4 = *(const fv4*)&h[(size_t)n * HDIM + 4 * d4];
            s0 += h4[0] * wt[4 * d4 + 0];
            s1 += h4[1] * wt[4 * d4 + 1];
            s2 += h4[2] * wt[4 * d4 + 2];
            s3 += h4[3] * wt[4 * d4 + 3];
        }
        out[(size_t)n * HDIM + lane] = (unsigned short)bf16r((s0 + s1) + (s2 + s3) + bb);
    }
}

// ---------------------------------------------------------------------------
// edge_mfma: out[t][c] = relu( max_{16 edges} ( relu(u[t]+v[src]) @ W2 )[c] + b2[c] )
// Wave handles 4 nodes = 64 edges. hrelu bf16 in chunk-XOR-swizzled LDS
// (wave-private tile -> NO barriers). GEMM on 16x16x32 bf16 MFMA; an M-tile
// of 16 edges == one node, so max = 4 in-lane regs + shfl_xor(16,32).
// W2 hi+lo fragments held in registers (loaded once). LDS = 32KB.
// ---------------------------------------------------------------------------
__global__ __launch_bounds__(256, 3) void edge_mfma_kernel(
    const unsigned short* __restrict__ U, const unsigned short* __restrict__ V,
    const int* __restrict__ src,
    const unsigned short* __restrict__ Whi, const unsigned short* __restrict__ Wlo,
    const float* __restrict__ b2, float* __restrict__ out)
{
    __shared__ __align__(16) unsigned short At[4][64 * 64];  // 4 waves x 8KB

    int tid  = threadIdx.x;
    int wave = tid >> 6;
    int lane = tid & 63;
    int quad = lane >> 4;
    int m    = lane & 15;

    int nodeBase  = blockIdx.x * 16 + wave * 4;
    long edgeBase = (long)nodeBase * 16;
    unsigned short* at = At[wave];

    // ---- B fragments (registers): B[n=c][k=j] rows of transposed W2 ----
    bf8 Bh[4][2], Bl[4][2];
#pragma unroll
    for (int nt = 0; nt < 4; ++nt)
#pragma unroll
        for (int ks = 0; ks < 2; ++ks) {
            int off = (nt * 16 + m) * 64 + ks * 32 + quad * 8;
            Bh[nt][ks] = *(const bf8*)&Whi[off];
            Bl[nt][ks] = *(const bf8*)&Wlo[off];
        }

    // ---- phase 1: hrelu -> swizzled bf16 LDS; 2 edges/iter (32ch pairs) ----
    int hh = lane >> 5;        // half-wave: edge parity
    int cp = lane & 31;        // channel pair: channels 2cp, 2cp+1
    int srcReg = src[edgeBase + lane];   // one coalesced row load, shfl later

    float ulo[4], uhi[4];
#pragma unroll
    for (int n = 0; n < 4; ++n) {
        unsigned up = *(const unsigned*)&U[(size_t)(nodeBase + n) * HDIM + 2 * cp];
        ulo[n] = bf16lo2f(up);
        uhi[n] = bf16hi2f(up);
    }

#pragma unroll
    for (int i = 0; i < 32; ++i) {
        int e = 2 * i + hh;
        int s = __shfl(srcReg, e);
        unsigned vp = *(const unsigned*)&V[(size_t)s * HDIM + 2 * cp];
        int n = i >> 3;        // == e>>4 (e=2i+hh, hh<2)
        float lo = fmaxf(ulo[n] + bf16lo2f(vp), 0.f);
        float hi = fmaxf(uhi[n] + bf16hi2f(vp), 0.f);
        unsigned pk = bf16r(lo) | (bf16r(hi) << 16);
        // byte addr: 128*e + ((chunk ^ (e&7))<<4) + ((4*cp)&15), chunk = cp>>2
        int addr = 128 * e + ((((cp >> 2) ^ (e & 7)) << 4)) + ((cp << 2) & 15);
        *(unsigned*)((char*)at + addr) = pk;
    }
    // wave-private tile: compiler inserts lgkmcnt waits; no barrier needed.

    float b2v = b2[lane];

    // ---- phase 2: per M-tile (= per node) ----
#pragma unroll
    for (int mt = 0; mt < 4; ++mt) {
        int e = mt * 16 + m;
        bf8 A[2];
#pragma unroll
        for (int ks = 0; ks < 2; ++ks) {
            int chunk = ks * 4 + quad;
            int addr = 128 * e + ((chunk ^ (e & 7)) << 4);
            A[ks] = *(const bf8*)((char*)at + addr);
        }
        f32x4 acc[4] = {{0,0,0,0},{0,0,0,0},{0,0,0,0},{0,0,0,0}};
#pragma unroll
        for (int ks = 0; ks < 2; ++ks)
#pragma unroll
            for (int nt = 0; nt < 4; ++nt) {
                acc[nt] = __builtin_amdgcn_mfma_f32_16x16x32_bf16(A[ks], Bl[nt][ks], acc[nt], 0, 0, 0);
                acc[nt] = __builtin_amdgcn_mfma_f32_16x16x32_bf16(A[ks], Bh[nt][ks], acc[nt], 0, 0, 0);
            }
        // C layout: col=lane&15, row=quad*4+reg -> rows = 16 edges of this node
        float mx[4];
#pragma unroll
        for (int nt = 0; nt < 4; ++nt)
            mx[nt] = fmaxf(fmaxf(acc[nt][0], acc[nt][1]), fmaxf(acc[nt][2], acc[nt][3]));
#pragma unroll
        for (int nt = 0; nt < 4; ++nt) {
            mx[nt] = fmaxf(mx[nt], __shfl_xor(mx[nt], 16));
            mx[nt] = fmaxf(mx[nt], __shfl_xor(mx[nt], 32));
        }
        // quad q stores channels q*16 + m  == channel `lane` of ntile==quad
        float val = (quad == 0) ? mx[0] : (quad == 1) ? mx[1] : (quad == 2) ? mx[2] : mx[3];
        out[(size_t)(nodeBase + mt) * HDIM + lane] = fmaxf(val + b2v, 0.f);
    }
}

// ---------------------------------------------------------------------------
// region mean accumulation
// ---------------------------------------------------------------------------
__global__ void region_mean_kernel(const float* __restrict__ h, const int* __restrict__ labels,
                                   float* __restrict__ qsums, int* __restrict__ qcnt, int N)
{
    __shared__ float ls[8 * 64];
    __shared__ int   lc[8];
    int tid  = threadIdx.x;
    int lane = tid & 63;
    int gw   = (blockIdx.x * blockDim.x + tid) >> 6;
    int tw   = (gridDim.x * blockDim.x) >> 6;

    float acc[8] = {0, 0, 0, 0, 0, 0, 0, 0};
    int   cnt[8] = {0, 0, 0, 0, 0, 0, 0, 0};

    for (int n = gw; n < N; n += tw) {
        int lbl = labels[n];
        float val = h[(size_t)n * HDIM + lane];
#pragma unroll
        for (int r = 0; r < 8; ++r) {
            acc[r] += (lbl == r) ? val : 0.f;
            cnt[r] += (lbl == r) ? 1 : 0;
        }
    }

    if (tid < 8) lc[tid] = 0;
    for (int idx = tid; idx < 512; idx += 256) ls[idx] = 0.f;
    __syncthreads();
#pragma unroll
    for (int r = 0; r < 8; ++r) atomicAdd(&ls[r * 64 + lane], acc[r]);
    if (lane == 0)
#pragma unroll
        for (int r = 0; r < 8; ++r) atomicAdd(&lc[r], cnt[r]);
    __syncthreads();
    for (int idx = tid; idx < 512; idx += 256) atomicAdd(&qsums[idx], ls[idx]);
    if (tid < 8) atomicAdd(&qcnt[tid], lc[tid]);
}

// ---------------------------------------------------------------------------
// tail: fully parallel quotient convs (8 nodes, 32 edges) + pool + linear.
// ---------------------------------------------------------------------------
#define EQ_MAX 64
__global__ void tail_kernel(const float* __restrict__ qsums, const int* __restrict__ qcnt,
                            const int* __restrict__ qei, int Eq,
                            const float* __restrict__ W31, const float* __restrict__ b31,
                            const float* __restrict__ W32, const float* __restrict__ b32,
                            const float* __restrict__ W41, const float* __restrict__ b41,
                            const float* __restrict__ W42, const float* __restrict__ b42,
                            const float* __restrict__ linW, const float* __restrict__ linb,
                            float* __restrict__ out)
{
    __shared__ float qx[512], uu[512], vv[512];
    __shared__ float hr[EQ_MAX * 64], me[EQ_MAX * 64];
    __shared__ __align__(16) float W2s[64 * 64];
    __shared__ int   qes[EQ_MAX], qet[EQ_MAX];
    __shared__ float emb[64];

    int tid = threadIdx.x;
    if (Eq > EQ_MAX) Eq = EQ_MAX;

    if (tid < Eq) { qes[tid] = qei[tid]; qet[tid] = qei[Eq + tid]; }
    for (int idx = tid; idx < 512; idx += 256) {
        int r = idx >> 6;
        int cc = qcnt[r];
        qx[idx] = (cc > 0) ? qsums[idx] / (float)cc : 0.f;
    }
    __syncthreads();

    for (int layer = 0; layer < 2; ++layer) {
        const float* W1p = layer ? W41 : W31;
        const float* b1p = layer ? b41 : b31;
        const float* W2p = layer ? W42 : W32;
        const float* b2p = layer ? b42 : b32;

        for (int idx = tid * 4; idx < 4096; idx += 1024)
            *(fv4*)&W2s[idx] = *(const fv4*)&W2p[idx];

        for (int idx = tid; idx < 512; idx += 256) {
            int t = idx >> 6, c = idx & 63;
            float su = 0.f, sv = 0.f;
#pragma unroll 8
            for (int d = 0; d < 64; ++d) {
                float hv = qx[t * 64 + d];
                float a = W1p[d * 64 + c];
                float b = W1p[(d + 64) * 64 + c];
                su += hv * (a - b);
                sv += hv * b;
            }
            uu[idx] = su + b1p[c];
            vv[idx] = sv;
        }
        __syncthreads();

        for (int idx = tid; idx < Eq * 64; idx += 256) {
            int e = idx >> 6, c = idx & 63;
            hr[idx] = fmaxf(uu[qet[e] * 64 + c] + vv[qes[e] * 64 + c], 0.f);
        }
        __syncthreads();

        {
            int c = tid & 63, e0 = tid >> 6;
            for (int e = e0; e < Eq; e += 4) {
                float acc = 0.f;
#pragma unroll 8
                for (int j = 0; j < 64; ++j)
                    acc += hr[e * 64 + j] * W2s[j * 64 + c];
                me[e * 64 + c] = acc;
            }
        }
        __syncthreads();

        for (int idx = tid; idx < 512; idx += 256) {
            int t = idx >> 6, c = idx & 63;
            float a = -INFINITY;
            for (int e = 0; e < Eq; ++e)
                if (qet[e] == t) a = fmaxf(a, me[e * 64 + c]);
            float vout = (a == -INFINITY) ? 0.f : (a + b2p[c]);
            qx[idx] = fmaxf(vout, 0.f);
        }
        __syncthreads();
    }

    if (tid < 64) {
        float s = 0.f;
        for (int r = 0; r < 8; ++r) s += qx[r * 64 + tid];
        emb[tid] = s;
    }
    __syncthreads();
    if (tid < 8) {
        float o = linb[tid];
        for (int c = 0; c < 64; ++c) o += emb[c] * linW[c * 8 + tid];
        out[tid] = o;
    }
}

// ---------------------------------------------------------------------------
extern "C" void kernel_launch(void* const* d_in, const int* in_sizes, int n_in,
                              void* d_out, int out_size, void* d_ws, size_t ws_size,
                              hipStream_t stream)
{
    const float* x    = (const float*)d_in[0];
    const float* pos  = (const float*)d_in[1];
    const int*   ei   = (const int*)d_in[2];
    const int*   lbl  = (const int*)d_in[3];
    const int*   qei  = (const int*)d_in[4];
    const float* W11 = (const float*)d_in[5];
    const float* b11 = (const float*)d_in[6];
    const float* W12 = (const float*)d_in[7];
    const float* b12 = (const float*)d_in[8];
    const float* W21 = (const float*)d_in[9];
    const float* b21 = (const float*)d_in[10];
    const float* W22 = (const float*)d_in[11];
    const float* b22 = (const float*)d_in[12];
    const float* W31 = (const float*)d_in[13];
    const float* b31 = (const float*)d_in[14];
    const float* W32 = (const float*)d_in[15];
    const float* b32 = (const float*)d_in[16];
    const float* W41 = (const float*)d_in[17];
    const float* b41 = (const float*)d_in[18];
    const float* W42 = (const float*)d_in[19];
    const float* b42 = (const float*)d_in[20];
    const float* linW = (const float*)d_in[21];
    const float* linb = (const float*)d_in[22];

    int N  = in_sizes[0] / 16;          // 100000
    int Eq = in_sizes[4] / 2;           // 32
    const int* src = ei;                // row 0 = src; tgt = repeat(arange(N),16)

    size_t NH = (size_t)N * HDIM;
    unsigned short* Ub  = (unsigned short*)d_ws;     // bf16 N*64
    unsigned short* Vb  = Ub + NH;                   // bf16 N*64
    float* hF           = (float*)(Vb + NH);         // fp32 N*64
    unsigned short* w2h1 = (unsigned short*)(hF + NH);
    unsigned short* w2l1 = w2h1 + 4096;
    unsigned short* w2h2 = w2l1 + 4096;
    unsigned short* w2l2 = w2h2 + 4096;
    float* qsums = (float*)(w2l2 + 4096);
    int*   qcnt  = (int*)(qsums + 512);

    hipMemsetAsync(qsums, 0, 512 * sizeof(float) + 8 * sizeof(int), stream);

    int edgeBlocks = N / 16;            // 6250

    w2prep_kernel<<<16, 256, 0, stream>>>(W12, W22, w2h1, w2l1, w2h2, w2l2);
    // conv1
    pre1_kernel<<<512, 256, 0, stream>>>(x, pos, W11, b11, Ub, Vb, N);
    edge_mfma_kernel<<<edgeBlocks, 256, 0, stream>>>(Ub, Vb, src, w2h1, w2l1, b12, hF);
    // conv2
    pre_wide_kernel<<<512, 256, 0, stream>>>(hF, W21, b21, Ub, Vb, N);
    edge_mfma_kernel<<<edgeBlocks, 256, 0, stream>>>(Ub, Vb, src, w2h2, w2l2, b22, hF);
    // quotient pooling + tail
    region_mean_kernel<<<128, 256, 0, stream>>>(hF, lbl, qsums, qcnt, N);
    tail_kernel<<<1, 256, 0, stream>>>(qsums, qcnt, qei, Eq,
                                       W31, b31, W32, b32,
                                       W41, b41, W42, b42,
                                       linW, linb, (float*)d_out);
}

// Round 4
// 364.485 us; speedup vs baseline: 3.0172x; 1.4039x over previous
//
#include <hip/hip_runtime.h>
#include <hip/hip_bf16.h>

typedef float fv4 __attribute__((ext_vector_type(4)));
using bf8   = __attribute__((ext_vector_type(8))) short;  // 8 bf16 = 4 VGPRs (MFMA A/B frag)
using f32x4 = __attribute__((ext_vector_type(4))) float;  // MFMA C/D frag

#define HDIM 64

// round-to-nearest-even fp32 -> bf16 bits
__device__ __forceinline__ unsigned bf16r(float f) {
    unsigned u = __float_as_uint(f);
    return (u + 0x7fffu + ((u >> 16) & 1u)) >> 16;
}
__device__ __forceinline__ float bf16lo2f(unsigned p) { return __uint_as_float(p << 16); }
__device__ __forceinline__ float bf16hi2f(unsigned p) { return __uint_as_float(p & 0xffff0000u); }
__device__ __forceinline__ float bfs2f(unsigned short s) { return __uint_as_float(((unsigned)s) << 16); }

// ---------------------------------------------------------------------------
// prep: (a) split W2 of conv1/conv2 into transposed bf16 hi/lo  [c][j]
//       (b) build combined pre-GEMM weight for conv2:
//           Wpre[c'][d], c'<64: (W1a-W1b)^T (U part), c'>=64: W1b^T (V part)
// hi+lo recovers ~16 mantissa bits -> no systematic weight-quant error.
// ---------------------------------------------------------------------------
__global__ void prep_kernel(const float* __restrict__ W2a, const float* __restrict__ W2b,
                            const float* __restrict__ W1c,
                            unsigned short* __restrict__ hiA, unsigned short* __restrict__ loA,
                            unsigned short* __restrict__ hiB, unsigned short* __restrict__ loB,
                            unsigned short* __restrict__ wph, unsigned short* __restrict__ wpl)
{
    int idx = blockIdx.x * 256 + threadIdx.x;
    if (idx < 4096) {
        int j = idx >> 6, c = idx & 63;
        float w = W2a[idx];
        unsigned h = bf16r(w);
        unsigned l = bf16r(w - __uint_as_float(h << 16));
        hiA[c * 64 + j] = (unsigned short)h; loA[c * 64 + j] = (unsigned short)l;
        w = W2b[idx];
        h = bf16r(w);
        l = bf16r(w - __uint_as_float(h << 16));
        hiB[c * 64 + j] = (unsigned short)h; loB[c * 64 + j] = (unsigned short)l;
    }
    if (idx < 8192) {
        int d = idx & 63, cp = idx >> 6;
        float w = (cp < 64) ? (W1c[d * 64 + cp] - W1c[(d + 64) * 64 + cp])
                            : W1c[(d + 64) * 64 + (cp - 64)];
        unsigned h = bf16r(w);
        unsigned l = bf16r(w - __uint_as_float(h << 16));
        wph[cp * 64 + d] = (unsigned short)h;
        wpl[cp * 64 + d] = (unsigned short)l;
    }
}

// ---------------------------------------------------------------------------
// pre1: u = [x|pos] @ (W1a - W1b) + b1 ; v = [x|pos] @ W1b   (D = 19)
// fp32 math, bf16 outputs. Grid 2048 (R3: 512 blocks grid-capped occupancy
// at 21% -> latency-bound).
// ---------------------------------------------------------------------------
__global__ void pre1_kernel(
    const float* __restrict__ x, const float* __restrict__ pos,
    const float* __restrict__ W1, const float* __restrict__ b1,
    unsigned short* __restrict__ U, unsigned short* __restrict__ V, int N)
{
    int lane = threadIdx.x & 63;
    int gw   = (blockIdx.x * blockDim.x + threadIdx.x) >> 6;
    int tw   = (gridDim.x * blockDim.x) >> 6;

    float wd[19], wb[19];
#pragma unroll
    for (int d = 0; d < 19; ++d) {
        float a = W1[d * HDIM + lane];
        float b = W1[(d + 19) * HDIM + lane];
        wd[d] = a - b;
        wb[d] = b;
    }
    float bb = b1[lane];

    for (int n = gw; n < N; n += tw) {
        float su = 0.f, sv = 0.f;
#pragma unroll
        for (int d4 = 0; d4 < 4; ++d4) {
            fv4 h4 = *(const fv4*)&x[(size_t)n * 16 + 4 * d4];
#pragma unroll
            for (int k = 0; k < 4; ++k) {
                su += h4[k] * wd[4 * d4 + k];
                sv += h4[k] * wb[4 * d4 + k];
            }
        }
#pragma unroll
        for (int d = 0; d < 3; ++d) {
            float h = pos[(size_t)n * 3 + d];
            su += h * wd[16 + d];
            sv += h * wb[16 + d];
        }
        U[(size_t)n * HDIM + lane] = (unsigned short)bf16r(su + bb);
        V[(size_t)n * HDIM + lane] = (unsigned short)bf16r(sv);
    }
}

// ---------------------------------------------------------------------------
// pre_mfma (conv2 layer-1): [N x 64] @ [64 x 128] on MFMA. Per wave: 16-node
// tile = 2 A-frag global loads + 32 MFMAs (hi+lo). B (Wpre hi/lo) in 128
// VGPRs, loaded once per wave. Replaces R3 pre_wide (130us, latency-bound,
// grid-capped occupancy). C layout: col=lane&15 = out-channel, row=quad*4+r
// = node.
// ---------------------------------------------------------------------------
__global__ __launch_bounds__(256, 2) void pre_mfma_kernel(
    const unsigned short* __restrict__ h,     // bf16 N x 64
    const unsigned short* __restrict__ Whi,   // bf16 [c' 0..127][d 0..63]
    const unsigned short* __restrict__ Wlo,
    const float* __restrict__ b1,
    unsigned short* __restrict__ U, unsigned short* __restrict__ V, int nTiles)
{
    int lane = threadIdx.x & 63;
    int quad = lane >> 4;
    int m    = lane & 15;
    int gw   = (blockIdx.x * blockDim.x + threadIdx.x) >> 6;
    int tw   = (gridDim.x * blockDim.x) >> 6;

    bf8 Bh[8][2], Bl[8][2];
#pragma unroll
    for (int nt = 0; nt < 8; ++nt)
#pragma unroll
        for (int ks = 0; ks < 2; ++ks) {
            int off = (nt * 16 + m) * 64 + ks * 32 + quad * 8;
            Bh[nt][ks] = *(const bf8*)&Whi[off];
            Bl[nt][ks] = *(const bf8*)&Wlo[off];
        }
    float bias[4];
#pragma unroll
    for (int nt = 0; nt < 4; ++nt) bias[nt] = b1[nt * 16 + m];

    for (int t = gw; t < nTiles; t += tw) {
        int base = t * 16;
        bf8 A[2];
#pragma unroll
        for (int ks = 0; ks < 2; ++ks)
            A[ks] = *(const bf8*)&h[(size_t)(base + m) * HDIM + ks * 32 + quad * 8];

        f32x4 acc[8] = {{0,0,0,0},{0,0,0,0},{0,0,0,0},{0,0,0,0},
                        {0,0,0,0},{0,0,0,0},{0,0,0,0},{0,0,0,0}};
#pragma unroll
        for (int ks = 0; ks < 2; ++ks)
#pragma unroll
            for (int nt = 0; nt < 8; ++nt) {
                acc[nt] = __builtin_amdgcn_mfma_f32_16x16x32_bf16(A[ks], Bl[nt][ks], acc[nt], 0, 0, 0);
                acc[nt] = __builtin_amdgcn_mfma_f32_16x16x32_bf16(A[ks], Bh[nt][ks], acc[nt], 0, 0, 0);
            }

#pragma unroll
        for (int nt = 0; nt < 8; ++nt) {
            float bv = (nt < 4) ? bias[nt] : 0.f;
            unsigned short* __restrict__ dst = (nt < 4) ? U : V;
            int cc = (nt & 3) * 16 + m;
#pragma unroll
            for (int r = 0; r < 4; ++r) {
                int node = base + quad * 4 + r;
                dst[(size_t)node * HDIM + cc] = (unsigned short)bf16r(acc[nt][r] + bv);
            }
        }
    }
}

// ---------------------------------------------------------------------------
// edge_mfma: out[t][c] = relu( max_{16 edges} ( relu(u[t]+v[src]) @ W2 )[c] + b2[c] )
// Wave = 4 nodes = 64 edges; wave-private swizzled LDS tile, no barriers;
// 16x16x32 bf16 MFMA, W2 hi/lo in registers. Output bf16 (R4: halves writes).
// ---------------------------------------------------------------------------
__global__ __launch_bounds__(256, 3) void edge_mfma_kernel(
    const unsigned short* __restrict__ U, const unsigned short* __restrict__ V,
    const int* __restrict__ src,
    const unsigned short* __restrict__ Whi, const unsigned short* __restrict__ Wlo,
    const float* __restrict__ b2, unsigned short* __restrict__ out)
{
    __shared__ __align__(16) unsigned short At[4][64 * 64];  // 4 waves x 8KB

    int tid  = threadIdx.x;
    int wave = tid >> 6;
    int lane = tid & 63;
    int quad = lane >> 4;
    int m    = lane & 15;

    int nodeBase  = blockIdx.x * 16 + wave * 4;
    long edgeBase = (long)nodeBase * 16;
    unsigned short* at = At[wave];

    bf8 Bh[4][2], Bl[4][2];
#pragma unroll
    for (int nt = 0; nt < 4; ++nt)
#pragma unroll
        for (int ks = 0; ks < 2; ++ks) {
            int off = (nt * 16 + m) * 64 + ks * 32 + quad * 8;
            Bh[nt][ks] = *(const bf8*)&Whi[off];
            Bl[nt][ks] = *(const bf8*)&Wlo[off];
        }

    int hh = lane >> 5;
    int cp = lane & 31;
    int srcReg = src[edgeBase + lane];

    float ulo[4], uhi[4];
#pragma unroll
    for (int n = 0; n < 4; ++n) {
        unsigned up = *(const unsigned*)&U[(size_t)(nodeBase + n) * HDIM + 2 * cp];
        ulo[n] = bf16lo2f(up);
        uhi[n] = bf16hi2f(up);
    }

#pragma unroll
    for (int i = 0; i < 32; ++i) {
        int e = 2 * i + hh;
        int s = __shfl(srcReg, e);
        unsigned vp = *(const unsigned*)&V[(size_t)s * HDIM + 2 * cp];
        int n = i >> 3;
        float lo = fmaxf(ulo[n] + bf16lo2f(vp), 0.f);
        float hi = fmaxf(uhi[n] + bf16hi2f(vp), 0.f);
        unsigned pk = bf16r(lo) | (bf16r(hi) << 16);
        int addr = 128 * e + ((((cp >> 2) ^ (e & 7)) << 4)) + ((cp << 2) & 15);
        *(unsigned*)((char*)at + addr) = pk;
    }

    float b2v = b2[lane];

#pragma unroll
    for (int mt = 0; mt < 4; ++mt) {
        int e = mt * 16 + m;
        bf8 A[2];
#pragma unroll
        for (int ks = 0; ks < 2; ++ks) {
            int chunk = ks * 4 + quad;
            int addr = 128 * e + ((chunk ^ (e & 7)) << 4);
            A[ks] = *(const bf8*)((char*)at + addr);
        }
        f32x4 acc[4] = {{0,0,0,0},{0,0,0,0},{0,0,0,0},{0,0,0,0}};
#pragma unroll
        for (int ks = 0; ks < 2; ++ks)
#pragma unroll
            for (int nt = 0; nt < 4; ++nt) {
                acc[nt] = __builtin_amdgcn_mfma_f32_16x16x32_bf16(A[ks], Bl[nt][ks], acc[nt], 0, 0, 0);
                acc[nt] = __builtin_amdgcn_mfma_f32_16x16x32_bf16(A[ks], Bh[nt][ks], acc[nt], 0, 0, 0);
            }
        float mx[4];
#pragma unroll
        for (int nt = 0; nt < 4; ++nt)
            mx[nt] = fmaxf(fmaxf(acc[nt][0], acc[nt][1]), fmaxf(acc[nt][2], acc[nt][3]));
#pragma unroll
        for (int nt = 0; nt < 4; ++nt) {
            mx[nt] = fmaxf(mx[nt], __shfl_xor(mx[nt], 16));
            mx[nt] = fmaxf(mx[nt], __shfl_xor(mx[nt], 32));
        }
        float val = (quad == 0) ? mx[0] : (quad == 1) ? mx[1] : (quad == 2) ? mx[2] : mx[3];
        out[(size_t)(nodeBase + mt) * HDIM + lane] =
            (unsigned short)bf16r(fmaxf(val + b2v, 0.f));
    }
}

// ---------------------------------------------------------------------------
// region mean accumulation (bf16 input; grid 1024 — R3's 128 blocks used
// half the CUs)
// ---------------------------------------------------------------------------
__global__ void region_mean_kernel(const unsigned short* __restrict__ h,
                                   const int* __restrict__ labels,
                                   float* __restrict__ qsums, int* __restrict__ qcnt, int N)
{
    __shared__ float ls[8 * 64];
    __shared__ int   lc[8];
    int tid  = threadIdx.x;
    int lane = tid & 63;
    int gw   = (blockIdx.x * blockDim.x + tid) >> 6;
    int tw   = (gridDim.x * blockDim.x) >> 6;

    float acc[8] = {0, 0, 0, 0, 0, 0, 0, 0};
    int   cnt[8] = {0, 0, 0, 0, 0, 0, 0, 0};

    for (int n = gw; n < N; n += tw) {
        int lbl = labels[n];
        float val = bfs2f(h[(size_t)n * HDIM + lane]);
#pragma unroll
        for (int r = 0; r < 8; ++r) {
            acc[r] += (lbl == r) ? val : 0.f;
            cnt[r] += (lbl == r) ? 1 : 0;
        }
    }

    if (tid < 8) lc[tid] = 0;
    for (int idx = tid; idx < 512; idx += 256) ls[idx] = 0.f;
    __syncthreads();
#pragma unroll
    for (int r = 0; r < 8; ++r) atomicAdd(&ls[r * 64 + lane], acc[r]);
    if (lane == 0)
#pragma unroll
        for (int r = 0; r < 8; ++r) atomicAdd(&lc[r], cnt[r]);
    __syncthreads();
    for (int idx = tid; idx < 512; idx += 256) atomicAdd(&qsums[idx], ls[idx]);
    if (tid < 8) atomicAdd(&qcnt[tid], lc[tid]);
}

// ---------------------------------------------------------------------------
// tail: fully parallel quotient convs (8 nodes, 32 edges) + pool + linear.
// ---------------------------------------------------------------------------
#define EQ_MAX 64
__global__ void tail_kernel(const float* __restrict__ qsums, const int* __restrict__ qcnt,
                            const int* __restrict__ qei, int Eq,
                            const float* __restrict__ W31, const float* __restrict__ b31,
                            const float* __restrict__ W32, const float* __restrict__ b32,
                            const float* __restrict__ W41, const float* __restrict__ b41,
                            const float* __restrict__ W42, const float* __restrict__ b42,
                            const float* __restrict__ linW, const float* __restrict__ linb,
                            float* __restrict__ out)
{
    __shared__ float qx[512], uu[512], vv[512];
    __shared__ float hr[EQ_MAX * 64], me[EQ_MAX * 64];
    __shared__ __align__(16) float W2s[64 * 64];
    __shared__ int   qes[EQ_MAX], qet[EQ_MAX];
    __shared__ float emb[64];

    int tid = threadIdx.x;
    if (Eq > EQ_MAX) Eq = EQ_MAX;

    if (tid < Eq) { qes[tid] = qei[tid]; qet[tid] = qei[Eq + tid]; }
    for (int idx = tid; idx < 512; idx += 256) {
        int r = idx >> 6;
        int cc = qcnt[r];
        qx[idx] = (cc > 0) ? qsums[idx] / (float)cc : 0.f;
    }
    __syncthreads();

    for (int layer = 0; layer < 2; ++layer) {
        const float* W1p = layer ? W41 : W31;
        const float* b1p = layer ? b41 : b31;
        const float* W2p = layer ? W42 : W32;
        const float* b2p = layer ? b42 : b32;

        for (int idx = tid * 4; idx < 4096; idx += 1024)
            *(fv4*)&W2s[idx] = *(const fv4*)&W2p[idx];

        for (int idx = tid; idx < 512; idx += 256) {
            int t = idx >> 6, c = idx & 63;
            float su = 0.f, sv = 0.f;
#pragma unroll 8
            for (int d = 0; d < 64; ++d) {
                float hv = qx[t * 64 + d];
                float a = W1p[d * 64 + c];
                float b = W1p[(d + 64) * 64 + c];
                su += hv * (a - b);
                sv += hv * b;
            }
            uu[idx] = su + b1p[c];
            vv[idx] = sv;
        }
        __syncthreads();

        for (int idx = tid; idx < Eq * 64; idx += 256) {
            int e = idx >> 6, c = idx & 63;
            hr[idx] = fmaxf(uu[qet[e] * 64 + c] + vv[qes[e] * 64 + c], 0.f);
        }
        __syncthreads();

        {
            int c = tid & 63, e0 = tid >> 6;
            for (int e = e0; e < Eq; e += 4) {
                float acc = 0.f;
#pragma unroll 8
                for (int j = 0; j < 64; ++j)
                    acc += hr[e * 64 + j] * W2s[j * 64 + c];
                me[e * 64 + c] = acc;
            }
        }
        __syncthreads();

        for (int idx = tid; idx < 512; idx += 256) {
            int t = idx >> 6, c = idx & 63;
            float a = -INFINITY;
            for (int e = 0; e < Eq; ++e)
                if (qet[e] == t) a = fmaxf(a, me[e * 64 + c]);
            float vout = (a == -INFINITY) ? 0.f : (a + b2p[c]);
            qx[idx] = fmaxf(vout, 0.f);
        }
        __syncthreads();
    }

    if (tid < 64) {
        float s = 0.f;
        for (int r = 0; r < 8; ++r) s += qx[r * 64 + tid];
        emb[tid] = s;
    }
    __syncthreads();
    if (tid < 8) {
        float o = linb[tid];
        for (int c = 0; c < 64; ++c) o += emb[c] * linW[c * 8 + tid];
        out[tid] = o;
    }
}

// ---------------------------------------------------------------------------
extern "C" void kernel_launch(void* const* d_in, const int* in_sizes, int n_in,
                              void* d_out, int out_size, void* d_ws, size_t ws_size,
                              hipStream_t stream)
{
    const float* x    = (const float*)d_in[0];
    const float* pos  = (const float*)d_in[1];
    const int*   ei   = (const int*)d_in[2];
    const int*   lbl  = (const int*)d_in[3];
    const int*   qei  = (const int*)d_in[4];
    const float* W11 = (const float*)d_in[5];
    const float* b11 = (const float*)d_in[6];
    const float* W12 = (const float*)d_in[7];
    const float* b12 = (const float*)d_in[8];
    const float* W21 = (const float*)d_in[9];
    const float* b21 = (const float*)d_in[10];
    const float* W22 = (const float*)d_in[11];
    const float* b22 = (const float*)d_in[12];
    const float* W31 = (const float*)d_in[13];
    const float* b31 = (const float*)d_in[14];
    const float* W32 = (const float*)d_in[15];
    const float* b32 = (const float*)d_in[16];
    const float* W41 = (const float*)d_in[17];
    const float* b41 = (const float*)d_in[18];
    const float* W42 = (const float*)d_in[19];
    const float* b42 = (const float*)d_in[20];
    const float* linW = (const float*)d_in[21];
    const float* linb = (const float*)d_in[22];

    int N  = in_sizes[0] / 16;          // 100000
    int Eq = in_sizes[4] / 2;           // 32
    const int* src = ei;                // row 0 = src; tgt = repeat(arange(N),16)

    size_t NH = (size_t)N * HDIM;
    unsigned short* hbf = (unsigned short*)d_ws;   // bf16 N*64 (h1, then h2)
    unsigned short* Ub  = hbf + NH;                // bf16 N*64
    unsigned short* Vb  = Ub + NH;                 // bf16 N*64
    unsigned short* w2h1 = Vb + NH;
    unsigned short* w2l1 = w2h1 + 4096;
    unsigned short* w2h2 = w2l1 + 4096;
    unsigned short* w2l2 = w2h2 + 4096;
    unsigned short* wph  = w2l2 + 4096;            // 8192
    unsigned short* wpl  = wph + 8192;             // 8192
    float* qsums = (float*)(wpl + 8192);
    int*   qcnt  = (int*)(qsums + 512);

    hipMemsetAsync(qsums, 0, 512 * sizeof(float) + 8 * sizeof(int), stream);

    int edgeBlocks = N / 16;            // 6250
    int nTiles     = N / 16;

    prep_kernel<<<32, 256, 0, stream>>>(W12, W22, W21, w2h1, w2l1, w2h2, w2l2, wph, wpl);
    // conv1
    pre1_kernel<<<2048, 256, 0, stream>>>(x, pos, W11, b11, Ub, Vb, N);
    edge_mfma_kernel<<<edgeBlocks, 256, 0, stream>>>(Ub, Vb, src, w2h1, w2l1, b12, hbf);
    // conv2
    pre_mfma_kernel<<<512, 256, 0, stream>>>(hbf, wph, wpl, b21, Ub, Vb, nTiles);
    edge_mfma_kernel<<<edgeBlocks, 256, 0, stream>>>(Ub, Vb, src, w2h2, w2l2, b22, hbf);
    // quotient pooling + tail
    region_mean_kernel<<<1024, 256, 0, stream>>>(hbf, lbl, qsums, qcnt, N);
    tail_kernel<<<1, 256, 0, stream>>>(qsums, qcnt, qei, Eq,
                                       W31, b31, W32, b32,
                                       W41, b41, W42, b42,
                                       linW, linb, (float*)d_out);
}